// Round 2
// baseline (862.883 us; speedup 1.0000x reference)
//
#include <hip/hip_runtime.h>
#include <hip/hip_bf16.h>

// MFMA fragment types (gfx950): 8 bf16 (as shorts) in 4 VGPRs; 4 fp32 acc.
typedef short s16x8 __attribute__((ext_vector_type(8)));
typedef float f32x4 __attribute__((ext_vector_type(4)));

#define BATCH 2048
#define KP    64      // patches per batch
#define DIN   768     // C*E*E
#define CF    64      // feature dim
// sharpness = CF * E*E*E * 4 = 64 * 4096 * 4
#define SHARPNESS 1048576.0f

// ---- fp32 -> bf16 RNE (bit trick; inputs are finite) ----------------------
__device__ __forceinline__ short bf16_rne(float x) {
    unsigned u = __float_as_uint(x);
    unsigned r = u + 0x7FFFu + ((u >> 16) & 1u);
    return (short)(r >> 16);
}
// a = hi + lo with both bf16; residual ~2^-18 relative.
__device__ __forceinline__ void split_bf16(float x, short& h, short& l) {
    short hb = bf16_rne(x);
    h = hb;
    float hf = __uint_as_float(((unsigned)(unsigned short)hb) << 16);
    l = bf16_rne(x - hf);
}

// ---------------------------------------------------------------------------
// Kernel 0: pre-split Wtheta and Wphi (64x768 fp32 each) into hi/lo bf16.
// grid 192 x 256 covers exactly 49152 elements of each.
// ---------------------------------------------------------------------------
__global__ __launch_bounds__(256) void convw_kernel(
    const float* __restrict__ Wt, const float* __restrict__ Wp,
    short* __restrict__ th, short* __restrict__ tl,
    short* __restrict__ ph, short* __restrict__ pl)
{
    int i = blockIdx.x * 256 + threadIdx.x;
    short h, l;
    split_bf16(Wt[i], h, l); th[i] = h; tl[i] = l;
    split_bf16(Wp[i], h, l); ph[i] = h; pl[i] = l;
}

// ---------------------------------------------------------------------------
// Kernel 1: x_feat[b,f] = l2norm_f( x_im[b,:] @ Wtheta[f,:] + btheta[f] )
// M=2048(b) N=64(f) K=768. 128 blocks x 16 rows; wave w -> cols w*16..+15.
// mfma_f32_16x16x32_bf16: A[m=lane&15][k=q*8+j], B[n=lane&15][k=q*8+j],
// D: row=(lane>>4)*4+r, col=lane&15  (m89/m91-verified mapping)
// Split-bf16: acc = ah*bh + ah*bl + al*bh  (3 MFMAs, ~fp32 accuracy)
// ---------------------------------------------------------------------------
__global__ __launch_bounds__(256) void xfeat_kernel(
    const float* __restrict__ x_im,
    const short* __restrict__ Wth_hi, const short* __restrict__ Wth_lo,
    const float* __restrict__ btheta,
    float* __restrict__ x_feat)
{
    __shared__ float raw[16][68];
    const int tid  = threadIdx.x;
    const int w    = tid >> 6;
    const int lane = tid & 63;
    const int mrow = lane & 15;
    const int q    = lane >> 4;
    const int b0   = blockIdx.x * 16;

    const float* Arow = x_im + (size_t)(b0 + mrow) * DIN + q * 8;
    const short* Bh   = Wth_hi + (size_t)(w * 16 + mrow) * DIN + q * 8;
    const short* Bl   = Wth_lo + (size_t)(w * 16 + mrow) * DIN + q * 8;

    f32x4 acc = {};
    for (int kk = 0; kk < DIN; kk += 32) {
        f32x4 f0 = *reinterpret_cast<const f32x4*>(Arow + kk);
        f32x4 f1 = *reinterpret_cast<const f32x4*>(Arow + kk + 4);
        s16x8 ah, al;
#pragma unroll
        for (int j = 0; j < 4; ++j) { short h, l; split_bf16(f0[j], h, l); ah[j] = h; al[j] = l; }
#pragma unroll
        for (int j = 0; j < 4; ++j) { short h, l; split_bf16(f1[j], h, l); ah[4 + j] = h; al[4 + j] = l; }
        s16x8 bh = *reinterpret_cast<const s16x8*>(Bh + kk);
        s16x8 bl = *reinterpret_cast<const s16x8*>(Bl + kk);
        acc = __builtin_amdgcn_mfma_f32_16x16x32_bf16(ah, bh, acc, 0, 0, 0);
        acc = __builtin_amdgcn_mfma_f32_16x16x32_bf16(ah, bl, acc, 0, 0, 0);
        acc = __builtin_amdgcn_mfma_f32_16x16x32_bf16(al, bh, acc, 0, 0, 0);
    }
#pragma unroll
    for (int r = 0; r < 4; ++r) {
        int row = q * 4 + r;
        int col = w * 16 + mrow;
        raw[row][col] = acc[r] + btheta[col];
    }
    __syncthreads();
    if (tid < 64) {  // wave 0: 16 rows x 4 segments
        int row = tid >> 2, seg = tid & 3;
        float ss = 0.f;
#pragma unroll
        for (int i = 0; i < 16; ++i) { float v = raw[row][seg * 16 + i]; ss += v * v; }
        ss += __shfl_xor(ss, 1, 64);
        ss += __shfl_xor(ss, 2, 64);
        float inv = 1.0f / fmaxf(sqrtf(ss), 1e-12f);
        float* dst = x_feat + (size_t)(b0 + row) * CF + seg * 16;
#pragma unroll
        for (int i = 0; i < 16; ++i) dst[i] = raw[row][seg * 16 + i] * inv;
    }
}

// ---------------------------------------------------------------------------
// Kernel 2: one block per batch b.
//  A) raw[k][f] = p_im[b,k,:] @ Wphi[f,:] + bphi[f]  (64x64x768, split-bf16)
//  B) scores[k] = dot(raw[k], x_feat[b]) / max(||raw[k]||, 1e-12)
//  C) softmax(SHARPNESS*scores) -> wts;  switch = sigmoid(max*scale+shift)
//  D) wsp[:] = sum_k wts[k] * p[b,k,:]   (skip underflowed wts — one-hot-ish)
//  E) out = x*(1-sw) + ((Wo@Wg)@wsp + Wo@bg+bo)*sw
// ---------------------------------------------------------------------------
__global__ __launch_bounds__(256) void attn_kernel(
    const float* __restrict__ x,
    const float* __restrict__ p,
    const float* __restrict__ p_im,
    const short* __restrict__ Wph_hi, const short* __restrict__ Wph_lo,
    const float* __restrict__ bphi,
    const float* __restrict__ Wg,  const float* __restrict__ bg,
    const float* __restrict__ Wo,  const float* __restrict__ bo,
    const float* __restrict__ sig_scale, const float* __restrict__ sig_shift,
    const float* __restrict__ x_feat,
    float* __restrict__ out)
{
    __shared__ float raw[64][68];
    __shared__ float scores_s[64];
    __shared__ float wts_s[64];
    __shared__ float wsp[768];
    __shared__ float Mc[3][3];
    __shared__ float bc[3];
    __shared__ float sw_s;

    const int tid  = threadIdx.x;
    const int w    = tid >> 6;
    const int lane = tid & 63;
    const int mrow = lane & 15;
    const int q    = lane >> 4;
    const int b    = blockIdx.x;

    // --- Phase A: GEMM (wave w -> rows w*16..+15, all 64 cols) -------------
    const float* Arow = p_im + (size_t)b * (KP * DIN)
                             + (size_t)(w * 16 + mrow) * DIN + q * 8;
    f32x4 acc[4] = {};
    for (int kk = 0; kk < DIN; kk += 32) {
        f32x4 f0 = *reinterpret_cast<const f32x4*>(Arow + kk);
        f32x4 f1 = *reinterpret_cast<const f32x4*>(Arow + kk + 4);
        s16x8 ah, al;
#pragma unroll
        for (int j = 0; j < 4; ++j) { short h, l; split_bf16(f0[j], h, l); ah[j] = h; al[j] = l; }
#pragma unroll
        for (int j = 0; j < 4; ++j) { short h, l; split_bf16(f1[j], h, l); ah[4 + j] = h; al[4 + j] = l; }
#pragma unroll
        for (int nt = 0; nt < 4; ++nt) {
            const size_t boff = (size_t)(nt * 16 + mrow) * DIN + kk + q * 8;
            s16x8 bh = *reinterpret_cast<const s16x8*>(Wph_hi + boff);
            s16x8 bl = *reinterpret_cast<const s16x8*>(Wph_lo + boff);
            acc[nt] = __builtin_amdgcn_mfma_f32_16x16x32_bf16(ah, bh, acc[nt], 0, 0, 0);
            acc[nt] = __builtin_amdgcn_mfma_f32_16x16x32_bf16(ah, bl, acc[nt], 0, 0, 0);
            acc[nt] = __builtin_amdgcn_mfma_f32_16x16x32_bf16(al, bh, acc[nt], 0, 0, 0);
        }
    }
#pragma unroll
    for (int nt = 0; nt < 4; ++nt)
#pragma unroll
        for (int r = 0; r < 4; ++r) {
            int row = w * 16 + q * 4 + r;   // A-row (patch k)
            int col = nt * 16 + mrow;       // B-row (feature f)
            raw[row][col] = acc[nt][r] + bphi[col];
        }
    __syncthreads();

    // --- Phase B: scores (4 threads per row, shuffle-combine) --------------
    {
        int row = tid >> 2, seg = tid & 3;
        const float* xf = x_feat + (size_t)b * CF + seg * 16;
        float ss = 0.f, dd = 0.f;
#pragma unroll
        for (int i = 0; i < 16; ++i) {
            float v = raw[row][seg * 16 + i];
            ss += v * v;
            dd += v * xf[i];
        }
        ss += __shfl_xor(ss, 1, 64); ss += __shfl_xor(ss, 2, 64);
        dd += __shfl_xor(dd, 1, 64); dd += __shfl_xor(dd, 2, 64);
        if (seg == 0) scores_s[row] = dd / fmaxf(sqrtf(ss), 1e-12f);
    }
#pragma unroll
    for (int j = 0; j < 3; ++j) wsp[j * 256 + tid] = 0.f;
    __syncthreads();

    // --- Phase C: softmax + switch (wave 0); 3x3 fold (threads 64..75) -----
    if (tid < 64) {
        float s = scores_s[tid];
        float m = s;
#pragma unroll
        for (int off = 1; off < 64; off <<= 1) m = fmaxf(m, __shfl_xor(m, off, 64));
        float e = expf(SHARPNESS * (s - m));
        float sum = e;
#pragma unroll
        for (int off = 1; off < 64; off <<= 1) sum += __shfl_xor(sum, off, 64);
        wts_s[tid] = e / sum;
        if (tid == 0) {
            float z = m * sig_scale[0] + sig_shift[0];
            sw_s = 1.0f / (1.0f + expf(-z));
        }
    } else if (tid < 76) {
        int idx = tid - 64;
        if (idx < 9) {                      // Mc = Wo @ Wg
            int o = idx / 3, c = idx % 3;
            float v = 0.f;
            for (int cc = 0; cc < 3; ++cc) v += Wo[o * 3 + cc] * Wg[cc * 3 + c];
            Mc[o][c] = v;
        } else {                            // bc = Wo @ bg + bo
            int o = idx - 9;
            float v = bo[o];
            for (int c = 0; c < 3; ++c) v += Wo[o * 3 + c] * bg[c];
            bc[o] = v;
        }
    }
    __syncthreads();

    // --- Phase D: selective weighted gather of p (block-uniform branch) ----
    const float* pb = p + (size_t)b * (KP * DIN);
    for (int k = 0; k < KP; ++k) {
        float wk = wts_s[k];
        if (wk > 1e-9f) {
#pragma unroll
            for (int j = 0; j < 3; ++j) {
                int i = j * 256 + tid;
                wsp[i] += wk * pb[k * DIN + i];
            }
        }
    }
    __syncthreads();

    // --- Phase E: channel mix + blend --------------------------------------
    float sw = sw_s;
    float g0 = wsp[tid], g1 = wsp[256 + tid], g2 = wsp[512 + tid];
#pragma unroll
    for (int o = 0; o < 3; ++o) {
        float pa = bc[o] + Mc[o][0] * g0 + Mc[o][1] * g1 + Mc[o][2] * g2;
        float xo = x[(size_t)b * DIN + o * 256 + tid];
        out[(size_t)b * DIN + o * 256 + tid] = xo * (1.0f - sw) + pa * sw;
    }
}

extern "C" void kernel_launch(void* const* d_in, const int* in_sizes, int n_in,
                              void* d_out, int out_size, void* d_ws, size_t ws_size,
                              hipStream_t stream) {
    const float* x       = (const float*)d_in[0];
    const float* p       = (const float*)d_in[1];
    const float* x_im    = (const float*)d_in[2];
    const float* p_im    = (const float*)d_in[3];
    const float* Wtheta  = (const float*)d_in[4];
    const float* btheta  = (const float*)d_in[5];
    const float* Wphi    = (const float*)d_in[6];
    const float* bphi    = (const float*)d_in[7];
    const float* Wg      = (const float*)d_in[8];
    const float* bg      = (const float*)d_in[9];
    const float* Wo      = (const float*)d_in[10];
    const float* bo      = (const float*)d_in[11];
    const float* sscale  = (const float*)d_in[12];
    const float* sshift  = (const float*)d_in[13];

    // ws layout: x_feat fp32 [2048*64] = 512 KB, then 4 short arrays of
    // 49152 elements (Wtheta hi/lo, Wphi hi/lo) = 4*96 KB. Total 896 KB.
    float* x_feat = (float*)d_ws;
    short* wth_hi = (short*)((char*)d_ws + 524288);
    short* wth_lo = wth_hi + 49152;
    short* wph_hi = wth_lo + 49152;
    short* wph_lo = wph_hi + 49152;

    convw_kernel<<<192, 256, 0, stream>>>(Wtheta, Wphi, wth_hi, wth_lo, wph_hi, wph_lo);
    xfeat_kernel<<<BATCH / 16, 256, 0, stream>>>(x_im, wth_hi, wth_lo, btheta, x_feat);
    attn_kernel<<<BATCH, 256, 0, stream>>>(x, p, p_im, wph_hi, wph_lo, bphi,
                                           Wg, bg, Wo, bo, sscale, sshift, x_feat,
                                           (float*)d_out);
}